// Round 12
// baseline (1039.518 us; speedup 1.0000x reference)
//
#include <hip/hip_runtime.h>
#include <hip/hip_bf16.h>
#include <math.h>

#define NN 50000
#define NE 1600000
#define BSH 7
#define RPB 128         // rows per bucket
#define NB 391          // ceil(NN/RPB)
#define BCAP 5120       // per-bucket staging cap (mean 4092, sigma ~64 -> +16 sigma)

typedef __attribute__((ext_vector_type(8))) short bf16x8;
typedef __attribute__((ext_vector_type(4))) float f32x4;

__device__ __forceinline__ short f2bf(float f) {
    return (short)((__float_as_uint(f) + 0x8000u) >> 16);
}
__device__ __forceinline__ float lo16(unsigned u) { return __uint_as_float(u << 16); }
__device__ __forceinline__ float hi16(unsigned u) { return __uint_as_float(u & 0xffff0000u); }
__device__ __forceinline__ unsigned enc_f(float f) {
    unsigned u = __float_as_uint(f);
    return (u & 0x80000000u) ? ~u : (u | 0x80000000u);
}
__device__ __forceinline__ float dec_f(unsigned e) {
    return (e & 0x80000000u) ? __uint_as_float(e & 0x7FFFFFFFu)
                             : __uint_as_float(~e);
}

// ============ setup: gcursor init + maxes zero + W0 pre-transpose ============
__global__ void setup_kernel(int* __restrict__ gcursor, unsigned* __restrict__ maxes,
                             const float* __restrict__ W, ushort* __restrict__ WTg) {
    int b = blockIdx.x;
    int t = threadIdx.x;
    if (b == 0) {
        for (int i = t; i < NB; i += 256) gcursor[i] = i * BCAP;
        if (t < 2) maxes[t] = 0u;
    } else {
        int i = (b - 1) * 256 + t;          // 64 blocks x 256 = 16384 = 64*256
        int n = i >> 8, k = i & 255;
        WTg[n * 264 + k] = (ushort)f2bf(W[k * 64 + n]);
    }
}

// ============ binA: LDS-binned scatter of packed (localrow<<16|col) ============
__global__ void __launch_bounds__(1024) binA_kernel(
        const int* __restrict__ row, const int* __restrict__ col,
        int* __restrict__ gcursor, unsigned* __restrict__ staging) {
    __shared__ unsigned lds_stage[8192];
    __shared__ unsigned lds_addr[8192];
    __shared__ int lds_cnt[512];
    __shared__ int lds_off[512];
    __shared__ int wg_goff[512];
    __shared__ int wls[8];
    int t = threadIdx.x;
    int lane = t & 63;
    int w = t >> 6;

    for (int cb = blockIdx.x * 8192; cb < NE; cb += gridDim.x * 8192) {
        int cnt_edges = NE - cb; if (cnt_edges > 8192) cnt_edges = 8192;
        if (t < 512) lds_cnt[t] = 0;
        __syncthreads();
        int myb[8]; int mylo[8]; unsigned mypk[8];
        int e0 = cb + t * 8;
        if (t * 8 + 7 < cnt_edges) {
            int4 r0 = *(const int4*)(row + e0);
            int4 r1 = *(const int4*)(row + e0 + 4);
            int4 c0 = *(const int4*)(col + e0);
            int4 c1 = *(const int4*)(col + e0 + 4);
            int rr[8] = {r0.x, r0.y, r0.z, r0.w, r1.x, r1.y, r1.z, r1.w};
            int cc[8] = {c0.x, c0.y, c0.z, c0.w, c1.x, c1.y, c1.z, c1.w};
            #pragma unroll
            for (int i = 0; i < 8; ++i) {
                int b = rr[i] >> BSH;
                myb[i] = b;
                mypk[i] = ((unsigned)(rr[i] & (RPB - 1)) << 16) | (unsigned)cc[i];
                mylo[i] = atomicAdd(&lds_cnt[b], 1);
            }
        } else {
            #pragma unroll
            for (int i = 0; i < 8; ++i) {
                int idx = t * 8 + i;
                myb[i] = -1;
                if (idx < cnt_edges) {
                    int e = cb + idx;
                    int r = row[e], c = col[e];
                    myb[i] = r >> BSH;
                    mypk[i] = ((unsigned)(r & (RPB - 1)) << 16) | (unsigned)c;
                    mylo[i] = atomicAdd(&lds_cnt[myb[i]], 1);
                }
            }
        }
        __syncthreads();
        // exclusive scan of lds_cnt[0..511] (8 waves)
        int v = 0, x = 0;
        if (t < 512) {
            v = lds_cnt[t];
            x = v;
            #pragma unroll
            for (int off = 1; off < 64; off <<= 1) {
                int y = __shfl_up(x, off);
                if (lane >= off) x += y;
            }
            if (lane == 63) wls[w] = x;
        }
        __syncthreads();
        if (t < 8) {
            int s = wls[t];
            #pragma unroll
            for (int off = 1; off < 8; off <<= 1) {
                int y = __shfl_up(s, off, 8);
                if ((t & 7) >= off) s += y;
            }
            wls[t] = s;
        }
        __syncthreads();
        if (t < 512) lds_off[t] = x - v + ((w > 0) ? wls[w - 1] : 0);
        if (t < NB) {
            int cc2 = lds_cnt[t];
            wg_goff[t] = cc2 ? atomicAdd(&gcursor[t], cc2) : 0;
        }
        __syncthreads();
        #pragma unroll
        for (int i = 0; i < 8; ++i) if (myb[i] >= 0) {
            int p = lds_off[myb[i]] + mylo[i];
            lds_stage[p] = mypk[i];
            lds_addr[p] = (unsigned)(wg_goff[myb[i]] + mylo[i]);
        }
        __syncthreads();
        for (int i = t; i < cnt_edges; i += 1024)
            staging[lds_addr[i]] = lds_stage[i];
        __syncthreads();
    }
}

// ============ pc-max reduction ============
__global__ void pcmax_kernel(const float* __restrict__ pc, unsigned* __restrict__ out) {
    int i = blockIdx.x * 256 + threadIdx.x;
    float v = (i < NN) ? pc[i] : -1e30f;
    #pragma unroll
    for (int off = 32; off; off >>= 1) v = fmaxf(v, __shfl_xor(v, off));
    if ((threadIdx.x & 63) == 0) atomicMax(out, enc_f(v));
}

// ============ layer0 GEMM (MFMA bf16): 2 row-tiles/wave + fused pc0-max ============
__global__ void __launch_bounds__(256) gemm0_kernel(
        const float* __restrict__ X,
        const ushort* __restrict__ WTg,
        const float* __restrict__ a,
        __hip_bfloat16* __restrict__ Hwb,
        float* __restrict__ pr,
        float* __restrict__ pc,
        unsigned* __restrict__ max0) {
    __shared__ ushort Wt[64 * 264];
    __shared__ unsigned bmax;
    int tid = threadIdx.x;
    if (tid == 0) bmax = 0u;
    {
        const uint* src = (const uint*)WTg;
        uint* dst = (uint*)Wt;
        for (int i = tid; i < 64 * 132; i += 256) dst[i] = src[i];
    }
    __syncthreads();
    int lane = tid & 63, wid = tid >> 6;
    int c = lane & 15, quad = lane >> 4;
    const ushort* wtp[4];
#pragma unroll
    for (int g = 0; g < 4; ++g) wtp[g] = &Wt[(g * 16 + c) * 264 + quad * 8];
    float aA[4], aB[4];
#pragma unroll
    for (int g = 0; g < 4; ++g) { aA[g] = a[g * 16 + c]; aB[g] = a[64 + g * 16 + c]; }

    int row0 = blockIdx.x * 128 + wid * 16;
    float qmax = -1e30f;

#pragma unroll
    for (int tt = 0; tt < 2; ++tt) {
        int rt = row0 + tt * 64;
        int arow = rt + c; if (arow >= NN) arow = NN - 1;
        const float* xbase = X + (size_t)arow * 256 + quad * 8;
        f32x4 acc[4];
#pragma unroll
        for (int g = 0; g < 4; ++g) acc[g] = (f32x4){0.f, 0.f, 0.f, 0.f};

#pragma unroll
        for (int k0 = 0; k0 < 256; k0 += 32) {
            float4 xa = *(const float4*)(xbase + k0);
            float4 xb = *(const float4*)(xbase + k0 + 4);
            bf16x8 af;
            af[0] = f2bf(xa.x); af[1] = f2bf(xa.y); af[2] = f2bf(xa.z); af[3] = f2bf(xa.w);
            af[4] = f2bf(xb.x); af[5] = f2bf(xb.y); af[6] = f2bf(xb.z); af[7] = f2bf(xb.w);
#pragma unroll
            for (int g = 0; g < 4; ++g) {
                bf16x8 bg = *(const bf16x8*)(wtp[g] + k0);
                acc[g] = __builtin_amdgcn_mfma_f32_16x16x32_bf16(af, bg, acc[g], 0, 0, 0);
            }
        }

#pragma unroll
        for (int r = 0; r < 4; ++r) {
            int row = rt + quad * 4 + r;
            float v0 = acc[0][r], v1 = acc[1][r], v2 = acc[2][r], v3 = acc[3][r];
            if (row < NN) {
                __hip_bfloat16* hp = Hwb + (size_t)row * 64 + c;
                hp[0]  = __float2bfloat16(v0);
                hp[16] = __float2bfloat16(v1);
                hp[32] = __float2bfloat16(v2);
                hp[48] = __float2bfloat16(v3);
            }
            float pv = v0 * aA[0] + v1 * aA[1] + v2 * aA[2] + v3 * aA[3];
            float qv = v0 * aB[0] + v1 * aB[1] + v2 * aB[2] + v3 * aB[3];
#pragma unroll
            for (int off = 8; off; off >>= 1) {
                pv += __shfl_xor(pv, off);
                qv += __shfl_xor(qv, off);
            }
            if (c == 0 && row < NN) { pr[row] = pv; pc[row] = qv; }
            if (row < NN) qmax = fmaxf(qmax, qv);
        }
    }
    qmax = fmaxf(qmax, __shfl_xor(qmax, 16));
    qmax = fmaxf(qmax, __shfl_xor(qmax, 32));
    if (lane == 0) atomicMax(&bmax, enc_f(qmax));
    __syncthreads();
    if (tid == 0) atomicMax(max0, bmax);   // 391 blocks -> safe atomic count
}

// ============ nodeA0: bucket-resident LDS accumulation + fused gemm1 ============
// block = 1 bucket (128 rows), 1024 thr. 16-lane groups gather 128B Hw0b rows.
__global__ void __launch_bounds__(1024) nodeA0_kernel(
        const int* __restrict__ gcursor,
        const unsigned* __restrict__ staging,
        const float* __restrict__ pr,
        const float* __restrict__ pc,
        const unsigned* __restrict__ pcmax,
        const ushort* __restrict__ Hwb,
        const float* __restrict__ W1,
        const float* __restrict__ a1,
        __hip_bfloat16* __restrict__ Hw1b,
        float* __restrict__ pr1,
        float* __restrict__ pc1) {
    __shared__ float acc[RPB * 65];          // pad 65: bank = (lr+4k+j)%32
    __shared__ float wsum[RPB];
    __shared__ float ms[RPB];
    __shared__ float prs[RPB];
    __shared__ unsigned long long wcb[1024];
    __shared__ float W1s[64 * 17];
    __shared__ float a1s[32];
    int b = blockIdx.x;
    int t = threadIdx.x;
    int rbase = b << BSH;
    int cnt = gcursor[b] - b * BCAP;
    if (cnt > BCAP) cnt = BCAP;
    const unsigned* sb = staging + (size_t)b * BCAP;
    float pm = dec_f(*pcmax);

    for (int i = t; i < RPB * 65; i += 1024) acc[i] = 0.f;
    for (int i = t; i < 64 * 16; i += 1024) W1s[(i >> 4) * 17 + (i & 15)] = W1[i];
    if (t < 32) a1s[t] = a1[t];
    if (t < RPB) {
        int gr = rbase + t;
        float p = (gr < NN) ? pr[gr] : 0.f;
        prs[t] = p;
        float m = p + pm;
        ms[t] = (m >= 0.f) ? m : 0.01f * m;
        wsum[t] = 0.f;
    }
    __syncthreads();

    int lane = t & 63;
    int g = t >> 4;          // 64 groups of 16
    int k = t & 15;

    for (int base = 0; base < cnt; base += 1024) {
        int S = cnt - base; if (S > 1024) S = 1024;
        // phase 1: per-edge weight
        float wgt = 0.f; unsigned pk = 0;
        if (t < S) {
            pk = sb[base + t];
            int lr = pk >> 16, cc = pk & 0xFFFF;
            float s = prs[lr] + pc[cc];
            s = (s >= 0.f) ? s : 0.01f * s;
            wgt = __expf(s - ms[lr]);
            atomicAdd(&wsum[lr], wgt);
        }
        wcb[t] = ((unsigned long long)pk << 32) | (unsigned long long)__float_as_uint(wgt);
        __syncthreads();
        // phase 2: group g handles edges e = g + 64*it (bank-spread ds_read)
        int iters = (S + 63) >> 6;
        #pragma unroll 2
        for (int it = 0; it < iters; ++it) {
            int e = g + (it << 6);
            if (e < S) {
                unsigned long long v = wcb[e];
                float we = __uint_as_float((unsigned)v);
                unsigned pk2 = (unsigned)(v >> 32);
                int lr = pk2 >> 16;
                int cc = pk2 & 0xFFFF;
                uint2 hv = *(const uint2*)(Hwb + (size_t)cc * 64 + k * 4);
                float* ap = &acc[lr * 65 + k * 4];
                atomicAdd(ap + 0, we * lo16(hv.x));
                atomicAdd(ap + 1, we * hi16(hv.x));
                atomicAdd(ap + 2, we * lo16(hv.y));
                atomicAdd(ap + 3, we * hi16(hv.y));
            }
        }
        __syncthreads();
    }

    // epilogue A: normalize + ELU in place
    for (int idx = t; idx < RPB * 64; idx += 1024) {
        int lr = idx >> 6, f = idx & 63;
        float ws = wsum[lr];
        float inv = (ws > 0.f) ? 1.f / ws : 0.f;
        float h = acc[lr * 65 + f] * inv;
        acc[lr * 65 + f] = (h > 0.f) ? h : (__expf(h) - 1.f);
    }
    __syncthreads();
    // epilogue B: fused gemm1 + pr1/pc1; wave handles 8 rows
    int wv = t >> 6;
    int j = lane & 15, p = lane >> 4;
    for (int rr = 0; rr < 8; ++rr) {
        int lr = wv * 8 + rr;
        int gr = rbase + lr;
        if (gr >= NN) break;
        const float* ar = &acc[lr * 65];
        float vj = 0.f;
        #pragma unroll
        for (int i = 0; i < 16; ++i)
            vj = fmaf(ar[p * 16 + i], W1s[(p * 16 + i) * 17 + j], vj);
        vj += __shfl_xor(vj, 16);
        vj += __shfl_xor(vj, 32);
        if (p == 0) Hw1b[(size_t)gr * 16 + j] = __float2bfloat16(vj);
        float pv = vj * a1s[j];
        float qv = vj * a1s[16 + j];
        #pragma unroll
        for (int off = 8; off; off >>= 1) {
            pv += __shfl_xor(pv, off);
            qv += __shfl_xor(qv, off);
        }
        if (lane == 0) { pr1[gr] = pv; pc1[gr] = qv; }
    }
}

// ============ nodeA1: bucket-resident LDS accumulation + log_softmax ============
__global__ void __launch_bounds__(1024) nodeA1_kernel(
        const int* __restrict__ gcursor,
        const unsigned* __restrict__ staging,
        const float* __restrict__ pr,
        const float* __restrict__ pc,
        const unsigned* __restrict__ pcmax,
        const ushort* __restrict__ Hwb,
        float* __restrict__ out) {
    __shared__ float acc[RPB * 17];          // pad 17
    __shared__ float wsum[RPB];
    __shared__ float ms[RPB];
    __shared__ float prs[RPB];
    __shared__ unsigned long long wcb[1024];
    int b = blockIdx.x;
    int t = threadIdx.x;
    int rbase = b << BSH;
    int cnt = gcursor[b] - b * BCAP;
    if (cnt > BCAP) cnt = BCAP;
    const unsigned* sb = staging + (size_t)b * BCAP;
    float pm = dec_f(*pcmax);

    for (int i = t; i < RPB * 17; i += 1024) acc[i] = 0.f;
    if (t < RPB) {
        int gr = rbase + t;
        float p = (gr < NN) ? pr[gr] : 0.f;
        prs[t] = p;
        float m = p + pm;
        ms[t] = (m >= 0.f) ? m : 0.01f * m;
        wsum[t] = 0.f;
    }
    __syncthreads();

    int lane = t & 63;
    int g = t >> 3;          // 128 groups of 8
    int k = t & 7;

    for (int base = 0; base < cnt; base += 1024) {
        int S = cnt - base; if (S > 1024) S = 1024;
        float wgt = 0.f; unsigned pk = 0;
        if (t < S) {
            pk = sb[base + t];
            int lr = pk >> 16, cc = pk & 0xFFFF;
            float s = prs[lr] + pc[cc];
            s = (s >= 0.f) ? s : 0.01f * s;
            wgt = __expf(s - ms[lr]);
            atomicAdd(&wsum[lr], wgt);
        }
        wcb[t] = ((unsigned long long)pk << 32) | (unsigned long long)__float_as_uint(wgt);
        __syncthreads();
        int iters = (S + 127) >> 7;
        #pragma unroll 2
        for (int it = 0; it < iters; ++it) {
            int e = g + (it << 7);
            if (e < S) {
                unsigned long long v = wcb[e];
                float we = __uint_as_float((unsigned)v);
                unsigned pk2 = (unsigned)(v >> 32);
                int lr = pk2 >> 16;
                int cc = pk2 & 0xFFFF;
                unsigned hv = *(const unsigned*)(Hwb + (size_t)cc * 16 + k * 2);
                float* ap = &acc[lr * 17 + k * 2];
                atomicAdd(ap + 0, we * lo16(hv));
                atomicAdd(ap + 1, we * hi16(hv));
            }
        }
        __syncthreads();
    }

    // epilogue: per-row log_softmax; wave handles 8 rows
    int wv = t >> 6;
    int j = lane & 15;
    for (int rr = 0; rr < 8; ++rr) {
        int lr = wv * 8 + rr;
        int gr = rbase + lr;
        if (gr >= NN) break;
        float ws = wsum[lr];
        float inv = (ws > 0.f) ? 1.f / ws : 0.f;
        float v = acc[lr * 17 + j] * inv;
        float mm = v;
        #pragma unroll
        for (int off = 8; off; off >>= 1) mm = fmaxf(mm, __shfl_xor(mm, off, 16));
        float ex = __expf(v - mm);
        float ssx = ex;
        #pragma unroll
        for (int off = 8; off; off >>= 1) ssx += __shfl_xor(ssx, off, 16);
        float r = v - (mm + __logf(ssx));
        if (lane < 16) out[(size_t)gr * 16 + j] = r;
    }
}

extern "C" void kernel_launch(void* const* d_in, const int* in_sizes, int n_in,
                              void* d_out, int out_size, void* d_ws, size_t ws_size,
                              hipStream_t stream) {
    const float* X  = (const float*)d_in[0];
    const int*   ei = (const int*)d_in[1];
    const float* W0 = (const float*)d_in[2];
    const float* a0 = (const float*)d_in[3];
    const float* W1 = (const float*)d_in[4];
    const float* a1 = (const float*)d_in[5];
    float* out = (float*)d_out;

    const int* row = ei;
    const int* col = ei + NE;

    char* wsb = (char*)d_ws;
    size_t off = 0;
    auto alloc = [&](size_t bytes) {
        void* p = wsb + off;
        off += (bytes + 15) & ~(size_t)15;
        return p;
    };
    unsigned* maxes = (unsigned*)alloc(16);        // [pcmax0, pcmax1], zeroed by setup
    int* gcursor    = (int*)alloc(512 * 4);
    unsigned* staging = (unsigned*)alloc((size_t)NB * BCAP * 4);
    ushort* WTg     = (ushort*)alloc((size_t)64 * 264 * 2);
    __hip_bfloat16* Hw0b = (__hip_bfloat16*)alloc((size_t)NN * 64 * 2);
    float* pr0      = (float*)alloc(NN * 4);
    float* pc0      = (float*)alloc(NN * 4);
    __hip_bfloat16* Hw1b = (__hip_bfloat16*)alloc((size_t)NN * 16 * 2);
    float* pr1      = (float*)alloc(NN * 4);
    float* pc1      = (float*)alloc(NN * 4);

    // setup: gcursor/maxes init + W0 transpose
    setup_kernel<<<65, 256, 0, stream>>>(gcursor, maxes, W0, WTg);
    // edge binning into fixed-capacity bucket staging
    binA_kernel<<<196, 1024, 0, stream>>>(row, col, gcursor, staging);
    // layer-0 GEMM (+ pc0-max fused)
    gemm0_kernel<<<(NN + 127) / 128, 256, 0, stream>>>(X, WTg, a0, Hw0b, pr0, pc0,
                                                       &maxes[0]);
    // layer 0 aggregate + ELU + fused layer-1 GEMM
    nodeA0_kernel<<<NB, 1024, 0, stream>>>(gcursor, staging, pr0, pc0, &maxes[0],
                                           (const ushort*)Hw0b, W1, a1,
                                           Hw1b, pr1, pc1);
    // layer 1
    pcmax_kernel<<<(NN + 255) / 256, 256, 0, stream>>>(pc1, &maxes[1]);
    nodeA1_kernel<<<NB, 1024, 0, stream>>>(gcursor, staging, pr1, pc1, &maxes[1],
                                           (const ushort*)Hw1b, out);
}

// Round 13
// 216.309 us; speedup vs baseline: 4.8057x; 4.8057x over previous
//
#include <hip/hip_runtime.h>
#include <hip/hip_bf16.h>
#include <math.h>

#define NN 50000
#define NE 1600000
#define BSH 9
#define BCK 98          // ceil(50000/512)
#define BCAP 20480      // per-bucket staging capacity (mean 16384, sigma ~127)

typedef __attribute__((ext_vector_type(8))) short bf16x8;
typedef __attribute__((ext_vector_type(4))) float f32x4;
typedef __attribute__((ext_vector_type(2))) float f32x2;

__device__ __forceinline__ short f2bf(float f) {
    return (short)((__float_as_uint(f) + 0x8000u) >> 16);
}
__device__ __forceinline__ float lo16(unsigned u) { return __uint_as_float(u << 16); }
__device__ __forceinline__ float hi16(unsigned u) { return __uint_as_float(u & 0xffff0000u); }
__device__ __forceinline__ unsigned enc_f(float f) {
    unsigned u = __float_as_uint(f);
    return (u & 0x80000000u) ? ~u : (u | 0x80000000u);
}
__device__ __forceinline__ float dec_f(unsigned e) {
    return (e & 0x80000000u) ? __uint_as_float(e & 0x7FFFFFFFu)
                             : __uint_as_float(~e);
}

// ============ CSR build (no global histogram) ============
__global__ void initcur_kernel(int* __restrict__ gcursor, unsigned* __restrict__ maxes) {
    int b = threadIdx.x;
    if (b < BCK) gcursor[b] = b * BCAP;
    if (b < 2) maxes[b] = 0u;
}

// Stage A: LDS-binned scatter of packed (localrow<<16|col) into fixed-capacity
// bucket-major staging slots. gcursor[b] starts at b*BCAP.
// Each thread owns 8 CONTIGUOUS edges -> int4-vectorized loads.
__global__ void __launch_bounds__(1024) binA_kernel(
        const int* __restrict__ row, const int* __restrict__ col,
        int* __restrict__ gcursor, unsigned* __restrict__ staging) {
    __shared__ unsigned lds_stage[8192];
    __shared__ unsigned lds_addr[8192];
    __shared__ int lds_cnt[128];
    __shared__ int lds_off[128];
    __shared__ int wg_goff[128];
    __shared__ int wtot[2];
    int t = threadIdx.x;
    int lane = t & 63;
    int w = t >> 6;

    for (int cb = blockIdx.x * 8192; cb < NE; cb += gridDim.x * 8192) {
        int cnt_edges = NE - cb; if (cnt_edges > 8192) cnt_edges = 8192;
        if (t < 128) lds_cnt[t] = 0;
        __syncthreads();
        int myb[8]; int mylo[8]; unsigned mypk[8];
        int e0 = cb + t * 8;
        if (t * 8 + 7 < cnt_edges) {
            int4 r0 = *(const int4*)(row + e0);
            int4 r1 = *(const int4*)(row + e0 + 4);
            int4 c0 = *(const int4*)(col + e0);
            int4 c1 = *(const int4*)(col + e0 + 4);
            int rr[8] = {r0.x, r0.y, r0.z, r0.w, r1.x, r1.y, r1.z, r1.w};
            int cc[8] = {c0.x, c0.y, c0.z, c0.w, c1.x, c1.y, c1.z, c1.w};
            #pragma unroll
            for (int i = 0; i < 8; ++i) {
                int b = rr[i] >> BSH;
                myb[i] = b;
                mypk[i] = ((unsigned)(rr[i] & 511) << 16) | (unsigned)cc[i];
                mylo[i] = atomicAdd(&lds_cnt[b], 1);
            }
        } else {
            #pragma unroll
            for (int i = 0; i < 8; ++i) {
                int idx = t * 8 + i;
                myb[i] = -1;
                if (idx < cnt_edges) {
                    int e = cb + idx;
                    int r = row[e], c = col[e];
                    myb[i] = r >> BSH;
                    mypk[i] = ((unsigned)(r & 511) << 16) | (unsigned)c;
                    mylo[i] = atomicAdd(&lds_cnt[myb[i]], 1);
                }
            }
        }
        __syncthreads();
        int v = (t < 128) ? lds_cnt[t] : 0;
        int x = v;
        #pragma unroll
        for (int off = 1; off < 64; off <<= 1) {
            int y = __shfl_up(x, off);
            if (lane >= off) x += y;
        }
        if (t < 128 && lane == 63) wtot[w] = x;
        __syncthreads();
        int add = (w == 1) ? wtot[0] : 0;
        if (t < 128) lds_off[t] = x - v + add;
        if (t < BCK) {
            int cc2 = lds_cnt[t];
            wg_goff[t] = cc2 ? atomicAdd(&gcursor[t], cc2) : 0;
        }
        __syncthreads();
        #pragma unroll
        for (int i = 0; i < 8; ++i) if (myb[i] >= 0) {
            int p = lds_off[myb[i]] + mylo[i];
            lds_stage[p] = mypk[i];
            lds_addr[p] = (unsigned)(wg_goff[myb[i]] + mylo[i]);
        }
        __syncthreads();
        for (int i = t; i < cnt_edges; i += 1024)
            staging[lds_addr[i]] = lds_stage[i];
        __syncthreads();
    }
}

// Bucket scan -> bbase[99]; also rowptr[NN] = NE.
__global__ void bucketscan_kernel(const int* __restrict__ gcursor,
                                  int* __restrict__ bbase,
                                  int* __restrict__ rowptr) {
    __shared__ int wt0;
    int t = threadIdx.x;
    int lane = t & 63;
    int w = t >> 6;
    int v = (t < BCK) ? (gcursor[t] - t * BCAP) : 0;
    int x = v;
    #pragma unroll
    for (int off = 1; off < 64; off <<= 1) {
        int y = __shfl_up(x, off);
        if (lane >= off) x += y;
    }
    if (w == 0 && lane == 63) wt0 = x;
    __syncthreads();
    int excl = x - v + ((w == 1) ? wt0 : 0);
    if (t < BCK) bbase[t] = excl;
    if (t == BCK - 1) { bbase[BCK] = excl + v; rowptr[NN] = excl + v; }
}

// Stage B: per-bucket local histogram + scan (writes rowptr slice), then
// LDS counting-scatter -> coalesced colperm (ushort) write. uint4 staging reads.
__global__ void __launch_bounds__(1024) binB_kernel(
        const int* __restrict__ bbase,
        const unsigned* __restrict__ staging,
        int* __restrict__ rowptr,
        ushort* __restrict__ colperm) {
    __shared__ int cur[512];
    __shared__ int lexcl[512];
    __shared__ int wls[8];
    __shared__ ushort lds_col[BCAP];
    int b = blockIdx.x;
    int t = threadIdx.x;
    int lane = t & 63;
    int w = t >> 6;
    int rbase = b << BSH;
    int nrows = NN - rbase; if (nrows > 512) nrows = 512;
    int gbase = bbase[b];
    int cnt = bbase[b + 1] - gbase;
    if (cnt > BCAP) cnt = BCAP;
    const unsigned* sb = staging + (size_t)b * BCAP;
    const uint4* sb4 = (const uint4*)sb;
    int cnt4 = cnt >> 2;

    if (t < 512) cur[t] = 0;
    __syncthreads();
    for (int i4 = t; i4 < cnt4; i4 += 1024) {
        uint4 e4 = sb4[i4];
        atomicAdd(&cur[e4.x >> 16], 1);
        atomicAdd(&cur[e4.y >> 16], 1);
        atomicAdd(&cur[e4.z >> 16], 1);
        atomicAdd(&cur[e4.w >> 16], 1);
    }
    for (int i = cnt4 * 4 + t; i < cnt; i += 1024)
        atomicAdd(&cur[sb[i] >> 16], 1);
    __syncthreads();
    int v = 0, x = 0;
    if (t < 512) {
        v = cur[t];
        x = v;
        #pragma unroll
        for (int off = 1; off < 64; off <<= 1) {
            int y = __shfl_up(x, off);
            if (lane >= off) x += y;
        }
        if (lane == 63) wls[w] = x;
    }
    __syncthreads();
    if (t < 8) {
        int s = wls[t];
        #pragma unroll
        for (int off = 1; off < 8; off <<= 1) {
            int y = __shfl_up(s, off, 8);
            if ((t & 7) >= off) s += y;
        }
        wls[t] = s;
    }
    __syncthreads();
    if (t < 512) {
        int e = x - v + ((w > 0) ? wls[w - 1] : 0);
        lexcl[t] = e;
        if (t < nrows) rowptr[rbase + t] = gbase + e;
    }
    __syncthreads();
    if (t < 512) cur[t] = lexcl[t];
    __syncthreads();
    for (int i4 = t; i4 < cnt4; i4 += 1024) {
        uint4 e4 = sb4[i4];
        int p0 = atomicAdd(&cur[e4.x >> 16], 1); lds_col[p0] = (ushort)(e4.x & 0xFFFFu);
        int p1 = atomicAdd(&cur[e4.y >> 16], 1); lds_col[p1] = (ushort)(e4.y & 0xFFFFu);
        int p2 = atomicAdd(&cur[e4.z >> 16], 1); lds_col[p2] = (ushort)(e4.z & 0xFFFFu);
        int p3 = atomicAdd(&cur[e4.w >> 16], 1); lds_col[p3] = (ushort)(e4.w & 0xFFFFu);
    }
    for (int i = cnt4 * 4 + t; i < cnt; i += 1024) {
        unsigned e = sb[i];
        int pos = atomicAdd(&cur[e >> 16], 1);
        lds_col[pos] = (ushort)(e & 0xFFFFu);
    }
    __syncthreads();
    for (int i = t; i < cnt; i += 1024)
        colperm[gbase + i] = lds_col[i];
}

// ============ pc-max reduction (few hundred atomics total — cheap) ============
__global__ void pcmax_kernel(const float* __restrict__ pc, unsigned* __restrict__ out) {
    int i = blockIdx.x * 256 + threadIdx.x;
    float v = (i < NN) ? pc[i] : -1e30f;
    #pragma unroll
    for (int off = 32; off; off >>= 1) v = fmaxf(v, __shfl_xor(v, off));
    if ((threadIdx.x & 63) == 0) atomicMax(out, enc_f(v));
}

// ============ W0 pre-transpose to bf16 padded [64][264] ============
__global__ void prep_kernel(const float* __restrict__ W, ushort* __restrict__ WTg) {
    int i = blockIdx.x * 256 + threadIdx.x;
    if (i >= 64 * 256) return;
    int n = i >> 8, k = i & 255;
    WTg[n * 264 + k] = (ushort)f2bf(W[k * 64 + n]);
}

// ============ layer0 GEMM (MFMA bf16): 2 row-tiles/wave + fused pc0-max ============
__global__ void __launch_bounds__(256) gemm0_kernel(
        const float* __restrict__ X,
        const ushort* __restrict__ WTg,
        const float* __restrict__ a,
        __hip_bfloat16* __restrict__ Hwb,
        float* __restrict__ pr,
        float* __restrict__ pc,
        unsigned* __restrict__ max0) {
    __shared__ ushort Wt[64 * 264];
    __shared__ unsigned bmax;
    int tid = threadIdx.x;
    if (tid == 0) bmax = 0u;
    {
        const uint* src = (const uint*)WTg;
        uint* dst = (uint*)Wt;
        for (int i = tid; i < 64 * 132; i += 256) dst[i] = src[i];
    }
    __syncthreads();
    int lane = tid & 63, wid = tid >> 6;
    int c = lane & 15, quad = lane >> 4;
    const ushort* wtp[4];
#pragma unroll
    for (int g = 0; g < 4; ++g) wtp[g] = &Wt[(g * 16 + c) * 264 + quad * 8];
    float aA[4], aB[4];
#pragma unroll
    for (int g = 0; g < 4; ++g) { aA[g] = a[g * 16 + c]; aB[g] = a[64 + g * 16 + c]; }

    int row0 = blockIdx.x * 128 + wid * 16;
    float qmax = -1e30f;

#pragma unroll
    for (int tt = 0; tt < 2; ++tt) {
        int rt = row0 + tt * 64;
        int arow = rt + c; if (arow >= NN) arow = NN - 1;
        const float* xbase = X + (size_t)arow * 256 + quad * 8;
        f32x4 acc[4];
#pragma unroll
        for (int g = 0; g < 4; ++g) acc[g] = (f32x4){0.f, 0.f, 0.f, 0.f};

#pragma unroll
        for (int k0 = 0; k0 < 256; k0 += 32) {
            float4 xa = *(const float4*)(xbase + k0);
            float4 xb = *(const float4*)(xbase + k0 + 4);
            bf16x8 af;
            af[0] = f2bf(xa.x); af[1] = f2bf(xa.y); af[2] = f2bf(xa.z); af[3] = f2bf(xa.w);
            af[4] = f2bf(xb.x); af[5] = f2bf(xb.y); af[6] = f2bf(xb.z); af[7] = f2bf(xb.w);
#pragma unroll
            for (int g = 0; g < 4; ++g) {
                bf16x8 bg = *(const bf16x8*)(wtp[g] + k0);
                acc[g] = __builtin_amdgcn_mfma_f32_16x16x32_bf16(af, bg, acc[g], 0, 0, 0);
            }
        }

#pragma unroll
        for (int r = 0; r < 4; ++r) {
            int row = rt + quad * 4 + r;
            float v0 = acc[0][r], v1 = acc[1][r], v2 = acc[2][r], v3 = acc[3][r];
            if (row < NN) {
                __hip_bfloat16* hp = Hwb + (size_t)row * 64 + c;
                hp[0]  = __float2bfloat16(v0);
                hp[16] = __float2bfloat16(v1);
                hp[32] = __float2bfloat16(v2);
                hp[48] = __float2bfloat16(v3);
            }
            float pv = v0 * aA[0] + v1 * aA[1] + v2 * aA[2] + v3 * aA[3];
            float qv = v0 * aB[0] + v1 * aB[1] + v2 * aB[2] + v3 * aB[3];
#pragma unroll
            for (int off = 8; off; off >>= 1) {
                pv += __shfl_xor(pv, off);
                qv += __shfl_xor(qv, off);
            }
            if (c == 0 && row < NN) { pr[row] = pv; pc[row] = qv; }
            if (row < NN) qmax = fmaxf(qmax, qv);
        }
    }
    qmax = fmaxf(qmax, __shfl_xor(qmax, 16));
    qmax = fmaxf(qmax, __shfl_xor(qmax, 32));
    if (lane == 0) atomicMax(&bmax, enc_f(qmax));
    __syncthreads();
    if (tid == 0) atomicMax(max0, bmax);   // 391 blocks -> safe atomic count
}

// ============ layer0 node kernel (fused gemm1; fast-math exp):
// lane=(k 0..15 feature-quad, q 0..3 edge slot); 8B gather per lane.
__global__ void __launch_bounds__(256) node0_kernel(
        const int* __restrict__ rowptr,
        const ushort* __restrict__ colperm,
        const float* __restrict__ pr,
        const float* __restrict__ pc,
        const unsigned* __restrict__ pcmax,
        const ushort* __restrict__ Hwb,
        const float* __restrict__ W1,
        const float* __restrict__ a1,
        __hip_bfloat16* __restrict__ Hw1b,
        float* __restrict__ pr1,
        float* __restrict__ pc1) {
    __shared__ float W1s[64 * 17];
    __shared__ float a1s[32];
    __shared__ float hbuf[4][64];
    __shared__ unsigned long long wcbuf[4][64];
    int t = threadIdx.x;
    for (int i = t; i < 64 * 16; i += 256)
        W1s[(i >> 4) * 17 + (i & 15)] = W1[i];
    if (t < 32) a1s[t] = a1[t];
    __syncthreads();

    int lane = t & 63;
    int wid = t >> 6;
    int node = blockIdx.x * 4 + wid;        // grid exact: 12500*4 == NN
    int k = lane & 15, q = lane >> 4;
    int start = rowptr[node], end = rowptr[node + 1];
    float pri = pr[node];
    float m = pri + dec_f(*pcmax);
    m = (m >= 0.f) ? m : 0.01f * m;

    float wsum = 0.f;
    f32x2 accA = {0.f, 0.f}, accB = {0.f, 0.f};
    for (int base = start; base < end; base += 64) {
        int n = end - base; if (n > 64) n = 64;
        float wv = 0.f; unsigned cv = 0;
        if (lane < n) {
            cv = (unsigned)colperm[base + lane];
            float s = pri + pc[cv];
            s = (s >= 0.f) ? s : 0.01f * s;
            wv = __expf(s - m);
        }
        wsum += wv;
        wcbuf[wid][lane] = ((unsigned long long)cv << 32) |
                           (unsigned long long)__float_as_uint(wv);
        int iters = (n + 3) >> 2;   // j = jj*4+q <= 63 always
        #pragma unroll 4
        for (int jj = 0; jj < iters; ++jj) {
            unsigned long long wc = wcbuf[wid][jj * 4 + q];
            float wj = __uint_as_float((unsigned)wc);
            int cj = (int)(wc >> 32);
            uint2 hv = *(const uint2*)(Hwb + (size_t)cj * 64 + k * 4);
            f32x2 wj2 = {wj, wj};
            f32x2 h01 = {lo16(hv.x), hi16(hv.x)};
            f32x2 h23 = {lo16(hv.y), hi16(hv.y)};
            accA += wj2 * h01;     // v_pk_fma_f32
            accB += wj2 * h23;
        }
    }
#pragma unroll
    for (int off = 32; off; off >>= 1) wsum += __shfl_xor(wsum, off);
    float acc0 = accA.x, acc1 = accA.y, acc2 = accB.x, acc3 = accB.y;
    acc0 += __shfl_xor(acc0, 16); acc0 += __shfl_xor(acc0, 32);
    acc1 += __shfl_xor(acc1, 16); acc1 += __shfl_xor(acc1, 32);
    acc2 += __shfl_xor(acc2, 16); acc2 += __shfl_xor(acc2, 32);
    acc3 += __shfl_xor(acc3, 16); acc3 += __shfl_xor(acc3, 32);

    float inv = (wsum > 0.f) ? 1.f / wsum : 0.f;
    float h0 = acc0 * inv; h0 = (h0 > 0.f) ? h0 : (__expf(h0) - 1.f);
    float h1 = acc1 * inv; h1 = (h1 > 0.f) ? h1 : (__expf(h1) - 1.f);
    float h2 = acc2 * inv; h2 = (h2 > 0.f) ? h2 : (__expf(h2) - 1.f);
    float h3 = acc3 * inv; h3 = (h3 > 0.f) ? h3 : (__expf(h3) - 1.f);
    if (q == 0) {
        float4 hh = {h0, h1, h2, h3};
        *(float4*)&hbuf[wid][k * 4] = hh;
    }
    // fused gemm1 (same-wave LDS produce->consume)
    int j = lane & 15, p = lane >> 4;
    const float* hbp = hbuf[wid];
    float vj = 0.f;
#pragma unroll
    for (int i = 0; i < 16; ++i) {
        int kk = p * 16 + i;
        vj = fmaf(hbp[kk], W1s[kk * 17 + j], vj);
    }
    vj += __shfl_xor(vj, 16);
    vj += __shfl_xor(vj, 32);
    if (p == 0) Hw1b[(size_t)node * 16 + j] = __float2bfloat16(vj);
    float pv = vj * a1s[j];
    float qv = vj * a1s[16 + j];
#pragma unroll
    for (int off = 8; off; off >>= 1) {
        pv += __shfl_xor(pv, off);
        qv += __shfl_xor(qv, off);
    }
    if (lane == 0) { pr1[node] = pv; pc1[node] = qv; }
}

// ============ layer1 node kernel: lane=(k 0..7 feat-pair, q 0..7 edge slot) ============
__global__ void __launch_bounds__(256) node1_kernel(
        const int* __restrict__ rowptr,
        const ushort* __restrict__ colperm,
        const float* __restrict__ pr,
        const float* __restrict__ pc,
        const unsigned* __restrict__ pcmax,
        const ushort* __restrict__ Hwb,
        float* __restrict__ out) {
    __shared__ unsigned long long wcbuf[4][64];
    int lane = threadIdx.x & 63;
    int wid = threadIdx.x >> 6;
    int node = blockIdx.x * 4 + wid;
    int k = lane & 7, q = lane >> 3;
    int start = rowptr[node], end = rowptr[node + 1];
    float pri = pr[node];
    float m = pri + dec_f(*pcmax);
    m = (m >= 0.f) ? m : 0.01f * m;

    float wsum = 0.f;
    f32x2 acc = {0.f, 0.f};
    for (int base = start; base < end; base += 64) {
        int n = end - base; if (n > 64) n = 64;
        float wv = 0.f; unsigned cv = 0;
        if (lane < n) {
            cv = (unsigned)colperm[base + lane];
            float s = pri + pc[cv];
            s = (s >= 0.f) ? s : 0.01f * s;
            wv = __expf(s - m);
        }
        wsum += wv;
        wcbuf[wid][lane] = ((unsigned long long)cv << 32) |
                           (unsigned long long)__float_as_uint(wv);
        int iters = (n + 7) >> 3;
        #pragma unroll 8
        for (int jj = 0; jj < iters; ++jj) {
            unsigned long long wc = wcbuf[wid][jj * 8 + q];
            float wj = __uint_as_float((unsigned)wc);
            int cj = (int)(wc >> 32);
            unsigned hv = *(const unsigned*)(Hwb + (size_t)cj * 16 + k * 2);
            f32x2 wj2 = {wj, wj};
            f32x2 h = {lo16(hv), hi16(hv)};
            acc += wj2 * h;
        }
    }
#pragma unroll
    for (int off = 32; off; off >>= 1) wsum += __shfl_xor(wsum, off);
    float a0 = acc.x, a1 = acc.y;
    a0 += __shfl_xor(a0, 8); a0 += __shfl_xor(a0, 16); a0 += __shfl_xor(a0, 32);
    a1 += __shfl_xor(a1, 8); a1 += __shfl_xor(a1, 16); a1 += __shfl_xor(a1, 32);
    float inv = (wsum > 0.f) ? 1.f / wsum : 0.f;
    float v0 = a0 * inv, v1 = a1 * inv;
    // log_softmax over 16 feats: width-8 butterflies over the k lanes
    float mm = fmaxf(v0, v1);
#pragma unroll
    for (int off = 1; off < 8; off <<= 1) mm = fmaxf(mm, __shfl_xor(mm, off, 8));
    float ssx = __expf(v0 - mm) + __expf(v1 - mm);
#pragma unroll
    for (int off = 1; off < 8; off <<= 1) ssx += __shfl_xor(ssx, off, 8);
    float lse = mm + __logf(ssx);
    if (q == 0) {
        float2 o = {v0 - lse, v1 - lse};
        *(float2*)(out + (size_t)node * 16 + k * 2) = o;
    }
}

extern "C" void kernel_launch(void* const* d_in, const int* in_sizes, int n_in,
                              void* d_out, int out_size, void* d_ws, size_t ws_size,
                              hipStream_t stream) {
    const float* X  = (const float*)d_in[0];
    const int*   ei = (const int*)d_in[1];
    const float* W0 = (const float*)d_in[2];
    const float* a0 = (const float*)d_in[3];
    const float* W1 = (const float*)d_in[4];
    const float* a1 = (const float*)d_in[5];
    float* out = (float*)d_out;

    const int* row = ei;
    const int* col = ei + NE;

    char* wsb = (char*)d_ws;
    size_t off = 0;
    auto alloc = [&](size_t bytes) {
        void* p = wsb + off;
        off += (bytes + 15) & ~(size_t)15;
        return p;
    };
    unsigned* maxes = (unsigned*)alloc(16);       // [pcmax0, pcmax1], zeroed by initcur
    int* rowptr     = (int*)alloc((NN + 2) * 4);
    int* gcursor    = (int*)alloc(128 * 4);
    int* bbase      = (int*)alloc(128 * 4);
    unsigned* staging = (unsigned*)alloc((size_t)BCK * BCAP * 4);
    ushort* colperm = (ushort*)alloc((size_t)NE * 2);
    ushort* WTg     = (ushort*)alloc((size_t)64 * 264 * 2);
    __hip_bfloat16* Hw0b = (__hip_bfloat16*)alloc((size_t)NN * 64 * 2);
    float* pr0      = (float*)alloc(NN * 4);
    float* pc0      = (float*)alloc(NN * 4);
    __hip_bfloat16* Hw1b = (__hip_bfloat16*)alloc((size_t)NN * 16 * 2);
    float* pr1      = (float*)alloc(NN * 4);
    float* pc1      = (float*)alloc(NN * 4);

    // CSR build (fixed-capacity bucket staging; no global histogram)
    initcur_kernel<<<1, 128, 0, stream>>>(gcursor, maxes);
    binA_kernel<<<196, 1024, 0, stream>>>(row, col, gcursor, staging);
    bucketscan_kernel<<<1, 128, 0, stream>>>(gcursor, bbase, rowptr);
    binB_kernel<<<BCK, 1024, 0, stream>>>(bbase, staging, rowptr, colperm);

    // layer 0 (+ fused layer-1 GEMM + fused pc0-max)
    prep_kernel<<<64, 256, 0, stream>>>(W0, WTg);
    gemm0_kernel<<<(NN + 127) / 128, 256, 0, stream>>>(X, WTg, a0, Hw0b, pr0, pc0,
                                                       &maxes[0]);
    node0_kernel<<<NN / 4, 256, 0, stream>>>(rowptr, colperm, pr0, pc0,
                                             &maxes[0], (const ushort*)Hw0b,
                                             W1, a1, Hw1b, pr1, pc1);

    // layer 1
    pcmax_kernel<<<(NN + 255) / 256, 256, 0, stream>>>(pc1, &maxes[1]);
    node1_kernel<<<NN / 4, 256, 0, stream>>>(rowptr, colperm, pr1, pc1,
                                             &maxes[1], (const ushort*)Hw1b, out);
}

// Round 14
// 213.444 us; speedup vs baseline: 4.8702x; 1.0134x over previous
//
#include <hip/hip_runtime.h>
#include <hip/hip_bf16.h>
#include <math.h>

#define NN 50000
#define NE 1600000
#define BSH 9
#define BCK 98          // ceil(50000/512)
#define BCAP 20480      // per-bucket staging capacity (mean 16384, sigma ~127)

typedef __attribute__((ext_vector_type(8))) short bf16x8;
typedef __attribute__((ext_vector_type(4))) float f32x4;
typedef __attribute__((ext_vector_type(2))) float f32x2;

__device__ __forceinline__ short f2bf(float f) {
    return (short)((__float_as_uint(f) + 0x8000u) >> 16);
}
__device__ __forceinline__ float lo16(unsigned u) { return __uint_as_float(u << 16); }
__device__ __forceinline__ float hi16(unsigned u) { return __uint_as_float(u & 0xffff0000u); }
__device__ __forceinline__ unsigned enc_f(float f) {
    unsigned u = __float_as_uint(f);
    return (u & 0x80000000u) ? ~u : (u | 0x80000000u);
}
__device__ __forceinline__ float dec_f(unsigned e) {
    return (e & 0x80000000u) ? __uint_as_float(e & 0x7FFFFFFFu)
                             : __uint_as_float(~e);
}

// ============ setup: gcursor init + maxes zero + W0 pre-transpose ============
__global__ void setup_kernel(int* __restrict__ gcursor, unsigned* __restrict__ maxes,
                             const float* __restrict__ W, ushort* __restrict__ WTg) {
    int b = blockIdx.x;
    int t = threadIdx.x;
    if (b == 0) {
        if (t < BCK) gcursor[t] = t * BCAP;
        if (t < 2) maxes[t] = 0u;
    } else {
        int i = (b - 1) * 256 + t;          // 64 blocks x 256 = 16384 = 64*256
        int n = i >> 8, k = i & 255;
        WTg[n * 264 + k] = (ushort)f2bf(W[k * 64 + n]);
    }
}

// Stage A: LDS-binned scatter of packed (localrow<<16|col) into fixed-capacity
// bucket-major staging slots. gcursor[b] starts at b*BCAP.
__global__ void __launch_bounds__(1024) binA_kernel(
        const int* __restrict__ row, const int* __restrict__ col,
        int* __restrict__ gcursor, unsigned* __restrict__ staging) {
    __shared__ unsigned lds_stage[8192];
    __shared__ unsigned lds_addr[8192];
    __shared__ int lds_cnt[128];
    __shared__ int lds_off[128];
    __shared__ int wg_goff[128];
    __shared__ int wtot[2];
    int t = threadIdx.x;
    int lane = t & 63;
    int w = t >> 6;

    for (int cb = blockIdx.x * 8192; cb < NE; cb += gridDim.x * 8192) {
        int cnt_edges = NE - cb; if (cnt_edges > 8192) cnt_edges = 8192;
        if (t < 128) lds_cnt[t] = 0;
        __syncthreads();
        int myb[8]; int mylo[8]; unsigned mypk[8];
        int e0 = cb + t * 8;
        if (t * 8 + 7 < cnt_edges) {
            int4 r0 = *(const int4*)(row + e0);
            int4 r1 = *(const int4*)(row + e0 + 4);
            int4 c0 = *(const int4*)(col + e0);
            int4 c1 = *(const int4*)(col + e0 + 4);
            int rr[8] = {r0.x, r0.y, r0.z, r0.w, r1.x, r1.y, r1.z, r1.w};
            int cc[8] = {c0.x, c0.y, c0.z, c0.w, c1.x, c1.y, c1.z, c1.w};
            #pragma unroll
            for (int i = 0; i < 8; ++i) {
                int b = rr[i] >> BSH;
                myb[i] = b;
                mypk[i] = ((unsigned)(rr[i] & 511) << 16) | (unsigned)cc[i];
                mylo[i] = atomicAdd(&lds_cnt[b], 1);
            }
        } else {
            #pragma unroll
            for (int i = 0; i < 8; ++i) {
                int idx = t * 8 + i;
                myb[i] = -1;
                if (idx < cnt_edges) {
                    int e = cb + idx;
                    int r = row[e], c = col[e];
                    myb[i] = r >> BSH;
                    mypk[i] = ((unsigned)(r & 511) << 16) | (unsigned)c;
                    mylo[i] = atomicAdd(&lds_cnt[myb[i]], 1);
                }
            }
        }
        __syncthreads();
        int v = (t < 128) ? lds_cnt[t] : 0;
        int x = v;
        #pragma unroll
        for (int off = 1; off < 64; off <<= 1) {
            int y = __shfl_up(x, off);
            if (lane >= off) x += y;
        }
        if (t < 128 && lane == 63) wtot[w] = x;
        __syncthreads();
        int add = (w == 1) ? wtot[0] : 0;
        if (t < 128) lds_off[t] = x - v + add;
        if (t < BCK) {
            int cc2 = lds_cnt[t];
            wg_goff[t] = cc2 ? atomicAdd(&gcursor[t], cc2) : 0;
        }
        __syncthreads();
        #pragma unroll
        for (int i = 0; i < 8; ++i) if (myb[i] >= 0) {
            int p = lds_off[myb[i]] + mylo[i];
            lds_stage[p] = mypk[i];
            lds_addr[p] = (unsigned)(wg_goff[myb[i]] + mylo[i]);
        }
        __syncthreads();
        for (int i = t; i < cnt_edges; i += 1024)
            staging[lds_addr[i]] = lds_stage[i];
        __syncthreads();
    }
}

// Stage B (single-pass, self-scanning): per-block bucket-prefix from gcursor,
// register-resident staging (read once), local histogram+scan -> rowptr slice,
// register scatter into LDS -> coalesced colperm write.
__global__ void __launch_bounds__(1024) binB_kernel(
        const int* __restrict__ gcursor,
        const unsigned* __restrict__ staging,
        int* __restrict__ rowptr,
        ushort* __restrict__ colperm) {
    __shared__ int bsc[128];    // bucket exclusive-scan partials
    __shared__ int bw[2];
    __shared__ int cur[512];
    __shared__ int wls8[8];
    __shared__ ushort lds_col[BCAP];
    int b = blockIdx.x;
    int t = threadIdx.x;
    int lane = t & 63;
    int w = t >> 6;

    // ---- bucket-level self-scan (threads 0..127) ----
    if (t < 128) {
        int v = 0;
        if (t < BCK) {
            v = gcursor[t] - t * BCAP;
            if (v > BCAP) v = BCAP;
        }
        int x = v;
        #pragma unroll
        for (int off = 1; off < 64; off <<= 1) {
            int y = __shfl_up(x, off);
            if (lane >= off) x += y;
        }
        if (lane == 63) bw[w] = x;
        bsc[t] = x - v;
    }
    __syncthreads();
    int gbase = bsc[b] + ((b >= 64) ? bw[0] : 0);
    int cnt = gcursor[b] - b * BCAP;
    if (cnt > BCAP) cnt = BCAP;
    if (b == 0 && t == 0) rowptr[NN] = bw[0] + bw[1];
    int rbase = b << BSH;
    int nrows = NN - rbase; if (nrows > 512) nrows = 512;
    const unsigned* sb = staging + (size_t)b * BCAP;

    // ---- load staging into registers (coalesced uint4), 20 edges/thread ----
    unsigned ev[20];
    #pragma unroll
    for (int j = 0; j < 5; ++j) {
        int i0 = t * 4 + j * 4096;
        uint4 val = {0u, 0u, 0u, 0u};
        if (i0 + 3 < cnt) {
            val = *(const uint4*)(sb + i0);
        } else {
            if (i0 + 0 < cnt) val.x = sb[i0 + 0];
            if (i0 + 1 < cnt) val.y = sb[i0 + 1];
            if (i0 + 2 < cnt) val.z = sb[i0 + 2];
            if (i0 + 3 < cnt) val.w = sb[i0 + 3];
        }
        ev[j * 4 + 0] = val.x; ev[j * 4 + 1] = val.y;
        ev[j * 4 + 2] = val.z; ev[j * 4 + 3] = val.w;
    }

    // ---- local histogram ----
    if (t < 512) cur[t] = 0;
    __syncthreads();
    #pragma unroll
    for (int j = 0; j < 5; ++j) {
        #pragma unroll
        for (int l = 0; l < 4; ++l) {
            int idx = t * 4 + j * 4096 + l;
            if (idx < cnt) atomicAdd(&cur[ev[j * 4 + l] >> 16], 1);
        }
    }
    __syncthreads();
    // ---- exclusive scan of 512 row-counts ----
    int v = 0, x = 0;
    if (t < 512) {
        v = cur[t];
        x = v;
        #pragma unroll
        for (int off = 1; off < 64; off <<= 1) {
            int y = __shfl_up(x, off);
            if (lane >= off) x += y;
        }
        if (lane == 63) wls8[w] = x;
    }
    __syncthreads();
    if (t < 8) {
        int s = wls8[t];
        #pragma unroll
        for (int off = 1; off < 8; off <<= 1) {
            int y = __shfl_up(s, off, 8);
            if ((t & 7) >= off) s += y;
        }
        wls8[t] = s;
    }
    __syncthreads();
    int excl = 0;
    if (t < 512) {
        excl = x - v + ((w > 0) ? wls8[w - 1] : 0);
        if (t < nrows) rowptr[rbase + t] = gbase + excl;
    }
    __syncthreads();
    if (t < 512) cur[t] = excl;
    __syncthreads();
    // ---- counting scatter from registers into LDS ----
    #pragma unroll
    for (int j = 0; j < 5; ++j) {
        #pragma unroll
        for (int l = 0; l < 4; ++l) {
            int idx = t * 4 + j * 4096 + l;
            if (idx < cnt) {
                unsigned e = ev[j * 4 + l];
                int pos = atomicAdd(&cur[e >> 16], 1);
                lds_col[pos] = (ushort)(e & 0xFFFFu);
            }
        }
    }
    __syncthreads();
    for (int i = t; i < cnt; i += 1024)
        colperm[gbase + i] = lds_col[i];
}

// ============ pc-max reduction (few hundred atomics total — cheap) ============
__global__ void pcmax_kernel(const float* __restrict__ pc, unsigned* __restrict__ out) {
    int i = blockIdx.x * 256 + threadIdx.x;
    float v = (i < NN) ? pc[i] : -1e30f;
    #pragma unroll
    for (int off = 32; off; off >>= 1) v = fmaxf(v, __shfl_xor(v, off));
    if ((threadIdx.x & 63) == 0) atomicMax(out, enc_f(v));
}

// ============ layer0 GEMM (MFMA bf16): 2 row-tiles/wave + fused pc0-max ============
__global__ void __launch_bounds__(256) gemm0_kernel(
        const float* __restrict__ X,
        const ushort* __restrict__ WTg,
        const float* __restrict__ a,
        __hip_bfloat16* __restrict__ Hwb,
        float* __restrict__ pr,
        float* __restrict__ pc,
        unsigned* __restrict__ max0) {
    __shared__ ushort Wt[64 * 264];
    __shared__ unsigned bmax;
    int tid = threadIdx.x;
    if (tid == 0) bmax = 0u;
    {
        const uint* src = (const uint*)WTg;
        uint* dst = (uint*)Wt;
        for (int i = tid; i < 64 * 132; i += 256) dst[i] = src[i];
    }
    __syncthreads();
    int lane = tid & 63, wid = tid >> 6;
    int c = lane & 15, quad = lane >> 4;
    const ushort* wtp[4];
#pragma unroll
    for (int g = 0; g < 4; ++g) wtp[g] = &Wt[(g * 16 + c) * 264 + quad * 8];
    float aA[4], aB[4];
#pragma unroll
    for (int g = 0; g < 4; ++g) { aA[g] = a[g * 16 + c]; aB[g] = a[64 + g * 16 + c]; }

    int row0 = blockIdx.x * 128 + wid * 16;
    float qmax = -1e30f;

#pragma unroll
    for (int tt = 0; tt < 2; ++tt) {
        int rt = row0 + tt * 64;
        int arow = rt + c; if (arow >= NN) arow = NN - 1;
        const float* xbase = X + (size_t)arow * 256 + quad * 8;
        f32x4 acc[4];
#pragma unroll
        for (int g = 0; g < 4; ++g) acc[g] = (f32x4){0.f, 0.f, 0.f, 0.f};

#pragma unroll
        for (int k0 = 0; k0 < 256; k0 += 32) {
            float4 xa = *(const float4*)(xbase + k0);
            float4 xb = *(const float4*)(xbase + k0 + 4);
            bf16x8 af;
            af[0] = f2bf(xa.x); af[1] = f2bf(xa.y); af[2] = f2bf(xa.z); af[3] = f2bf(xa.w);
            af[4] = f2bf(xb.x); af[5] = f2bf(xb.y); af[6] = f2bf(xb.z); af[7] = f2bf(xb.w);
#pragma unroll
            for (int g = 0; g < 4; ++g) {
                bf16x8 bg = *(const bf16x8*)(wtp[g] + k0);
                acc[g] = __builtin_amdgcn_mfma_f32_16x16x32_bf16(af, bg, acc[g], 0, 0, 0);
            }
        }

#pragma unroll
        for (int r = 0; r < 4; ++r) {
            int row = rt + quad * 4 + r;
            float v0 = acc[0][r], v1 = acc[1][r], v2 = acc[2][r], v3 = acc[3][r];
            if (row < NN) {
                __hip_bfloat16* hp = Hwb + (size_t)row * 64 + c;
                hp[0]  = __float2bfloat16(v0);
                hp[16] = __float2bfloat16(v1);
                hp[32] = __float2bfloat16(v2);
                hp[48] = __float2bfloat16(v3);
            }
            float pv = v0 * aA[0] + v1 * aA[1] + v2 * aA[2] + v3 * aA[3];
            float qv = v0 * aB[0] + v1 * aB[1] + v2 * aB[2] + v3 * aB[3];
#pragma unroll
            for (int off = 8; off; off >>= 1) {
                pv += __shfl_xor(pv, off);
                qv += __shfl_xor(qv, off);
            }
            if (c == 0 && row < NN) { pr[row] = pv; pc[row] = qv; }
            if (row < NN) qmax = fmaxf(qmax, qv);
        }
    }
    qmax = fmaxf(qmax, __shfl_xor(qmax, 16));
    qmax = fmaxf(qmax, __shfl_xor(qmax, 32));
    if (lane == 0) atomicMax(&bmax, enc_f(qmax));
    __syncthreads();
    if (tid == 0) atomicMax(max0, bmax);   // 391 blocks -> safe atomic count
}

// ============ layer0 node kernel (fused gemm1; fast-math exp):
// lane=(k 0..15 feature-quad, q 0..3 edge slot); 8B gather per lane.
__global__ void __launch_bounds__(256) node0_kernel(
        const int* __restrict__ rowptr,
        const ushort* __restrict__ colperm,
        const float* __restrict__ pr,
        const float* __restrict__ pc,
        const unsigned* __restrict__ pcmax,
        const ushort* __restrict__ Hwb,
        const float* __restrict__ W1,
        const float* __restrict__ a1,
        __hip_bfloat16* __restrict__ Hw1b,
        float* __restrict__ pr1,
        float* __restrict__ pc1) {
    __shared__ float W1s[64 * 17];
    __shared__ float a1s[32];
    __shared__ float hbuf[4][64];
    __shared__ unsigned long long wcbuf[4][64];
    int t = threadIdx.x;
    for (int i = t; i < 64 * 16; i += 256)
        W1s[(i >> 4) * 17 + (i & 15)] = W1[i];
    if (t < 32) a1s[t] = a1[t];
    __syncthreads();

    int lane = t & 63;
    int wid = t >> 6;
    int node = blockIdx.x * 4 + wid;        // grid exact: 12500*4 == NN
    int k = lane & 15, q = lane >> 4;
    int start = rowptr[node], end = rowptr[node + 1];
    float pri = pr[node];
    float m = pri + dec_f(*pcmax);
    m = (m >= 0.f) ? m : 0.01f * m;

    float wsum = 0.f;
    f32x2 accA = {0.f, 0.f}, accB = {0.f, 0.f};
    for (int base = start; base < end; base += 64) {
        int n = end - base; if (n > 64) n = 64;
        float wv = 0.f; unsigned cv = 0;
        if (lane < n) {
            cv = (unsigned)colperm[base + lane];
            float s = pri + pc[cv];
            s = (s >= 0.f) ? s : 0.01f * s;
            wv = __expf(s - m);
        }
        wsum += wv;
        wcbuf[wid][lane] = ((unsigned long long)cv << 32) |
                           (unsigned long long)__float_as_uint(wv);
        int iters = (n + 3) >> 2;   // j = jj*4+q <= 63 always
        #pragma unroll 4
        for (int jj = 0; jj < iters; ++jj) {
            unsigned long long wc = wcbuf[wid][jj * 4 + q];
            float wj = __uint_as_float((unsigned)wc);
            int cj = (int)(wc >> 32);
            uint2 hv = *(const uint2*)(Hwb + (size_t)cj * 64 + k * 4);
            f32x2 wj2 = {wj, wj};
            f32x2 h01 = {lo16(hv.x), hi16(hv.x)};
            f32x2 h23 = {lo16(hv.y), hi16(hv.y)};
            accA += wj2 * h01;     // v_pk_fma_f32
            accB += wj2 * h23;
        }
    }
#pragma unroll
    for (int off = 32; off; off >>= 1) wsum += __shfl_xor(wsum, off);
    float acc0 = accA.x, acc1 = accA.y, acc2 = accB.x, acc3 = accB.y;
    acc0 += __shfl_xor(acc0, 16); acc0 += __shfl_xor(acc0, 32);
    acc1 += __shfl_xor(acc1, 16); acc1 += __shfl_xor(acc1, 32);
    acc2 += __shfl_xor(acc2, 16); acc2 += __shfl_xor(acc2, 32);
    acc3 += __shfl_xor(acc3, 16); acc3 += __shfl_xor(acc3, 32);

    float inv = (wsum > 0.f) ? 1.f / wsum : 0.f;
    float h0 = acc0 * inv; h0 = (h0 > 0.f) ? h0 : (__expf(h0) - 1.f);
    float h1 = acc1 * inv; h1 = (h1 > 0.f) ? h1 : (__expf(h1) - 1.f);
    float h2 = acc2 * inv; h2 = (h2 > 0.f) ? h2 : (__expf(h2) - 1.f);
    float h3 = acc3 * inv; h3 = (h3 > 0.f) ? h3 : (__expf(h3) - 1.f);
    if (q == 0) {
        float4 hh = {h0, h1, h2, h3};
        *(float4*)&hbuf[wid][k * 4] = hh;
    }
    // fused gemm1 (same-wave LDS produce->consume)
    int j = lane & 15, p = lane >> 4;
    const float* hbp = hbuf[wid];
    float vj = 0.f;
#pragma unroll
    for (int i = 0; i < 16; ++i) {
        int kk = p * 16 + i;
        vj = fmaf(hbp[kk], W1s[kk * 17 + j], vj);
    }
    vj += __shfl_xor(vj, 16);
    vj += __shfl_xor(vj, 32);
    if (p == 0) Hw1b[(size_t)node * 16 + j] = __float2bfloat16(vj);
    float pv = vj * a1s[j];
    float qv = vj * a1s[16 + j];
#pragma unroll
    for (int off = 8; off; off >>= 1) {
        pv += __shfl_xor(pv, off);
        qv += __shfl_xor(qv, off);
    }
    if (lane == 0) { pr1[node] = pv; pc1[node] = qv; }
}

// ============ layer1 node kernel: lane=(k 0..7 feat-pair, q 0..7 edge slot) ============
__global__ void __launch_bounds__(256) node1_kernel(
        const int* __restrict__ rowptr,
        const ushort* __restrict__ colperm,
        const float* __restrict__ pr,
        const float* __restrict__ pc,
        const unsigned* __restrict__ pcmax,
        const ushort* __restrict__ Hwb,
        float* __restrict__ out) {
    __shared__ unsigned long long wcbuf[4][64];
    int lane = threadIdx.x & 63;
    int wid = threadIdx.x >> 6;
    int node = blockIdx.x * 4 + wid;
    int k = lane & 7, q = lane >> 3;
    int start = rowptr[node], end = rowptr[node + 1];
    float pri = pr[node];
    float m = pri + dec_f(*pcmax);
    m = (m >= 0.f) ? m : 0.01f * m;

    float wsum = 0.f;
    f32x2 acc = {0.f, 0.f};
    for (int base = start; base < end; base += 64) {
        int n = end - base; if (n > 64) n = 64;
        float wv = 0.f; unsigned cv = 0;
        if (lane < n) {
            cv = (unsigned)colperm[base + lane];
            float s = pri + pc[cv];
            s = (s >= 0.f) ? s : 0.01f * s;
            wv = __expf(s - m);
        }
        wsum += wv;
        wcbuf[wid][lane] = ((unsigned long long)cv << 32) |
                           (unsigned long long)__float_as_uint(wv);
        int iters = (n + 7) >> 3;
        #pragma unroll 8
        for (int jj = 0; jj < iters; ++jj) {
            unsigned long long wc = wcbuf[wid][jj * 8 + q];
            float wj = __uint_as_float((unsigned)wc);
            int cj = (int)(wc >> 32);
            unsigned hv = *(const unsigned*)(Hwb + (size_t)cj * 16 + k * 2);
            f32x2 wj2 = {wj, wj};
            f32x2 h = {lo16(hv), hi16(hv)};
            acc += wj2 * h;
        }
    }
#pragma unroll
    for (int off = 32; off; off >>= 1) wsum += __shfl_xor(wsum, off);
    float a0 = acc.x, a1 = acc.y;
    a0 += __shfl_xor(a0, 8); a0 += __shfl_xor(a0, 16); a0 += __shfl_xor(a0, 32);
    a1 += __shfl_xor(a1, 8); a1 += __shfl_xor(a1, 16); a1 += __shfl_xor(a1, 32);
    float inv = (wsum > 0.f) ? 1.f / wsum : 0.f;
    float v0 = a0 * inv, v1 = a1 * inv;
    // log_softmax over 16 feats: width-8 butterflies over the k lanes
    float mm = fmaxf(v0, v1);
#pragma unroll
    for (int off = 1; off < 8; off <<= 1) mm = fmaxf(mm, __shfl_xor(mm, off, 8));
    float ssx = __expf(v0 - mm) + __expf(v1 - mm);
#pragma unroll
    for (int off = 1; off < 8; off <<= 1) ssx += __shfl_xor(ssx, off, 8);
    float lse = mm + __logf(ssx);
    if (q == 0) {
        float2 o = {v0 - lse, v1 - lse};
        *(float2*)(out + (size_t)node * 16 + k * 2) = o;
    }
}

extern "C" void kernel_launch(void* const* d_in, const int* in_sizes, int n_in,
                              void* d_out, int out_size, void* d_ws, size_t ws_size,
                              hipStream_t stream) {
    const float* X  = (const float*)d_in[0];
    const int*   ei = (const int*)d_in[1];
    const float* W0 = (const float*)d_in[2];
    const float* a0 = (const float*)d_in[3];
    const float* W1 = (const float*)d_in[4];
    const float* a1 = (const float*)d_in[5];
    float* out = (float*)d_out;

    const int* row = ei;
    const int* col = ei + NE;

    char* wsb = (char*)d_ws;
    size_t off = 0;
    auto alloc = [&](size_t bytes) {
        void* p = wsb + off;
        off += (bytes + 15) & ~(size_t)15;
        return p;
    };
    unsigned* maxes = (unsigned*)alloc(16);       // [pcmax0, pcmax1], zeroed by setup
    int* rowptr     = (int*)alloc((NN + 2) * 4);
    int* gcursor    = (int*)alloc(128 * 4);
    unsigned* staging = (unsigned*)alloc((size_t)BCK * BCAP * 4);
    ushort* colperm = (ushort*)alloc((size_t)NE * 2);
    ushort* WTg     = (ushort*)alloc((size_t)64 * 264 * 2);
    __hip_bfloat16* Hw0b = (__hip_bfloat16*)alloc((size_t)NN * 64 * 2);
    float* pr0      = (float*)alloc(NN * 4);
    float* pc0      = (float*)alloc(NN * 4);
    __hip_bfloat16* Hw1b = (__hip_bfloat16*)alloc((size_t)NN * 16 * 2);
    float* pr1      = (float*)alloc(NN * 4);
    float* pc1      = (float*)alloc(NN * 4);

    // setup (gcursor/maxes init + W0 transpose), then CSR build
    setup_kernel<<<65, 256, 0, stream>>>(gcursor, maxes, W0, WTg);
    binA_kernel<<<196, 1024, 0, stream>>>(row, col, gcursor, staging);
    binB_kernel<<<BCK, 1024, 0, stream>>>(gcursor, staging, rowptr, colperm);

    // layer 0 (+ fused layer-1 GEMM + fused pc0-max)
    gemm0_kernel<<<(NN + 127) / 128, 256, 0, stream>>>(X, WTg, a0, Hw0b, pr0, pc0,
                                                       &maxes[0]);
    node0_kernel<<<NN / 4, 256, 0, stream>>>(rowptr, colperm, pr0, pc0,
                                             &maxes[0], (const ushort*)Hw0b,
                                             W1, a1, Hw1b, pr1, pc1);

    // layer 1
    pcmax_kernel<<<(NN + 255) / 256, 256, 0, stream>>>(pc1, &maxes[1]);
    node1_kernel<<<NN / 4, 256, 0, stream>>>(rowptr, colperm, pr1, pc1,
                                             &maxes[1], (const ushort*)Hw1b, out);
}